// Round 15
// baseline (212.272 us; speedup 1.0000x reference)
//
#include <hip/hip_runtime.h>
#include <hip/hip_bf16.h>
#include <math.h>

#define N_PTS 8192
#define C_IN  256
#define OUT_C 256
#define NSAMP 16
#define H_W   32
#define EPSBN 1e-5f
#define GDIM  8
#define NCELL (GDIM * GDIM * GDIM)
#define CAPC  768
#define CAP_H 64

typedef short bf16x8 __attribute__((ext_vector_type(8)));
typedef float f32x4  __attribute__((ext_vector_type(4)));

// EXACT arithmetic from the passing rounds: plain expression, default
// compiler contraction, shared by all scans. Do NOT change the rounding.
__device__ __forceinline__ float dist2(const float4 a, const float4 b) {
  float dot = a.x * b.x + a.y * b.y + a.z * b.z;
  return a.w + b.w - 2.0f * dot;
}

__device__ __forceinline__ unsigned long long make_key(float d, int j) {
  unsigned int di = __float_as_uint(d);
  unsigned int ord = ((int)di >= 0) ? (di ^ 0x80000000u) : ~di;
  return ((unsigned long long)ord << 32) | (unsigned int)j;
}

__device__ __forceinline__ void chain_insert(unsigned long long (&ak)[16], unsigned long long key) {
  if (key < ak[0]) {
    #pragma unroll
    for (int s = 0; s < 15; ++s) {
      unsigned long long mn = ak[s] < key ? ak[s] : key;
      unsigned long long nx = ak[s + 1];
      ak[s] = nx > mn ? nx : mn;
    }
    ak[15] = ak[15] < key ? ak[15] : key;
  }
}

// bf16 bit helpers (same rounding as __float2bfloat16 / widening as HW)
__device__ __forceinline__ float b2f(short s) {
  return __uint_as_float(((unsigned int)(unsigned short)s) << 16);
}
__device__ __forceinline__ short f2b(float v) {
  __hip_bfloat16 h = __float2bfloat16(v);
  short s;
  __builtin_memcpy(&s, &h, 2);
  return s;
}

// ---------------------------------------------------------------- prep
__global__ __launch_bounds__(256) void prep_kernel(
    const float* __restrict__ p,
    const float* __restrict__ wq, const float* __restrict__ wk, const float* __restrict__ wv,
    const float* __restrict__ bq, const float* __restrict__ bk, const float* __restrict__ bv,
    const float* __restrict__ l1w, const float* __restrict__ l2w,
    const float* __restrict__ bn1g, const float* __restrict__ bn1b,
    const float* __restrict__ bn1m, const float* __restrict__ bn1v,
    float4* __restrict__ p4, __hip_bfloat16* __restrict__ Bp, float* __restrict__ biasp,
    __hip_bfloat16* __restrict__ l1wp, __hip_bfloat16* __restrict__ l2wp,
    float* __restrict__ sc1, float* __restrict__ of1,
    int* __restrict__ cursor, int* __restrict__ pt_cell) {
  int tid = blockIdx.x * blockDim.x + threadIdx.x;
  if (tid < 48 * 32 * 16 * 8) {
    int kj = tid & 7, n = (tid >> 3) & 15, kb = (tid >> 7) & 31, nt = tid >> 12;
    int k = kb * 8 + kj, col = nt * 16 + n;
    float v;
    if (col < 256)      v = wq[k * 256 + col];
    else if (col < 512) v = wk[k * 256 + (col - 256)];
    else                v = wv[k * 256 + (col - 512)];
    Bp[tid] = __float2bfloat16(v);
  }
  if (tid < 768) {
    biasp[tid] = tid < 256 ? bq[tid] : (tid < 512 ? bk[tid - 256] : bv[tid - 512]);
  }
  if (tid < 8192) {
    int kj = tid & 7, n = (tid >> 3) & 15, kb = (tid >> 7) & 31, nt = (tid >> 12) & 1;
    int k = kb * 8 + kj, col = nt * 16 + n;
    l1wp[tid] = __float2bfloat16(l1w[k * 32 + col]);
  }
  if (tid < 1024) {
    int kj = tid & 7, n = (tid >> 3) & 15, kb = (tid >> 7) & 3, nt = (tid >> 9) & 1;
    int k = kb * 8 + kj, col = nt * 16 + n;
    l2wp[tid] = __float2bfloat16(l2w[k * 32 + col]);
  }
  if (tid < 256) {
    float s1 = bn1g[tid] * rsqrtf(bn1v[tid] + EPSBN);
    sc1[tid] = s1;
    of1[tid] = bn1b[tid] - bn1m[tid] * s1;
  }
  if (tid < NCELL) cursor[tid] = 0;
  if (tid < N_PTS) {
    float px = p[tid * 3 + 0], py = p[tid * 3 + 1], pz = p[tid * 3 + 2];
    float sq = px * px;
    sq += py * py;
    sq += pz * pz;
    p4[tid] = make_float4(px, py, pz, sq);
    int cx = min(GDIM - 1, max(0, (int)(px * GDIM)));
    int cy = min(GDIM - 1, max(0, (int)(py * GDIM)));
    int cz = min(GDIM - 1, max(0, (int)(pz * GDIM)));
    pt_cell[tid] = (cz * GDIM + cy) * GDIM + cx;
  }
}

// ---------------------------------------------------------------- scatter: in-block LDS histogram + scan + scatter
__global__ __launch_bounds__(512) void scatter_scan(
    const float4* __restrict__ p4, const int* __restrict__ pt_cell,
    int* __restrict__ cell_start, int* __restrict__ cursor,
    float4* __restrict__ sp4, int* __restrict__ sidx, int* __restrict__ rank) {
  __shared__ int buf[NCELL];
  const int t = threadIdx.x;
  buf[t] = 0;
  __syncthreads();
  for (int i = t; i < N_PTS; i += 512) atomicAdd(&buf[pt_cell[i]], 1);
  __syncthreads();
  for (int off = 1; off < NCELL; off <<= 1) {
    int add = (t >= off) ? buf[t - off] : 0;
    __syncthreads();
    buf[t] += add;
    __syncthreads();
  }
  if (blockIdx.x == 0) {
    cell_start[t + 1] = buf[t];
    if (t == 0) cell_start[0] = 0;
  }
  const int pid = blockIdx.x * 512 + t;
  const int c = pt_cell[pid];
  const int start = (c == 0) ? 0 : buf[c - 1];
  const int pos = start + atomicAdd(&cursor[c], 1);
  sp4[pos] = p4[pid];
  sidx[pos] = pid;
  rank[pid] = pos;
}

// ---------------------------------------------------------------- qkv gemm: bf16 MFMA, 64x32 per wave (3 waves/SIMD)
__global__ __launch_bounds__(256) void gemm_qkv_mfma(
    const float* __restrict__ x, const int* __restrict__ sidx,
    const __hip_bfloat16* __restrict__ Bp,
    const float* __restrict__ biasp, __hip_bfloat16* __restrict__ xqkv) {
  const int w = threadIdx.x >> 6;
  const int lane = threadIdx.x & 63;
  const int gw = blockIdx.x * 4 + w;          // 3072 waves
  const int m0 = (gw & 127) * 64;
  const int nt2 = (gw >> 7) * 2;              // 24 n-groups of 2 tiles (32 cols)
  const int n = lane & 15, q = lane >> 4;

  int o[4];
  #pragma unroll
  for (int mi = 0; mi < 4; ++mi) o[mi] = sidx[m0 + mi * 16 + n];

  f32x4 acc[4][2];
  #pragma unroll
  for (int mi = 0; mi < 4; ++mi)
    #pragma unroll
    for (int ni = 0; ni < 2; ++ni) acc[mi][ni] = (f32x4){0.f, 0.f, 0.f, 0.f};

  for (int k0 = 0; k0 < 256; k0 += 32) {
    bf16x8 af[4], bfr[2];
    #pragma unroll
    for (int mi = 0; mi < 4; ++mi) {
      const float* xr = &x[(size_t)o[mi] * 256 + k0 + q * 8];
      float4 xa = *(const float4*)xr;
      float4 xb = *(const float4*)(xr + 4);
      af[mi][0] = f2b(xa.x); af[mi][1] = f2b(xa.y);
      af[mi][2] = f2b(xa.z); af[mi][3] = f2b(xa.w);
      af[mi][4] = f2b(xb.x); af[mi][5] = f2b(xb.y);
      af[mi][6] = f2b(xb.z); af[mi][7] = f2b(xb.w);
    }
    #pragma unroll
    for (int ni = 0; ni < 2; ++ni)
      bfr[ni] = *(const bf16x8*)&Bp[(size_t)(nt2 + ni) * 4096 + (k0 >> 3) * 128 + q * 128 + n * 8];
    #pragma unroll
    for (int mi = 0; mi < 4; ++mi)
      #pragma unroll
      for (int ni = 0; ni < 2; ++ni)
        acc[mi][ni] = __builtin_amdgcn_mfma_f32_16x16x32_bf16(af[mi], bfr[ni], acc[mi][ni], 0, 0, 0);
  }
  #pragma unroll
  for (int ni = 0; ni < 2; ++ni) {
    int col = (nt2 + ni) * 16 + n;
    float b = biasp[col];
    #pragma unroll
    for (int mi = 0; mi < 4; ++mi)
      #pragma unroll
      for (int r = 0; r < 4; ++r)
        xqkv[(size_t)(m0 + mi * 16 + q * 4 + r) * 768 + col] = __float2bfloat16(acc[mi][ni][r] + b);
  }
}

// ---------------------------------------------------------------- exact grid KNN v6 (unchanged from R14)
__global__ __launch_bounds__(256) void knn_grid(
    const float4* __restrict__ sp4, const int* __restrict__ sidx,
    const int* __restrict__ cell_start, int* __restrict__ nbr) {
  __shared__ float4 cpos[CAPC];
  __shared__ int    cidx[CAPC];
  __shared__ unsigned long long hk_s[4][CAP_H];
  __shared__ unsigned long long okey_s[4][16];
  __shared__ int cnt_s[4];
  __shared__ int cell_s0_s[27];
  __shared__ int len_s[27];
  __shared__ int pref_s[28];
  __shared__ int nc_s, total_s;

  const int cell = blockIdx.x >> 2;
  const int sub  = blockIdx.x & 3;
  const int tid = threadIdx.x;
  const int hcx = cell & 7, hcy = (cell >> 3) & 7, hcz = cell >> 6;
  const int cs = cell_start[cell], ce = cell_start[cell + 1];

  const int ax0 = max(hcx - 1, 0), ax1 = min(hcx + 1, GDIM - 1);
  const int ay0 = max(hcy - 1, 0), ay1 = min(hcy + 1, GDIM - 1);
  const int az0 = max(hcz - 1, 0), az1 = min(hcz + 1, GDIM - 1);
  const int nx = ax1 - ax0 + 1, ny = ay1 - ay0 + 1, nz = az1 - az0 + 1;
  const int nbc = nx * ny * nz;

  if (tid < nbc) {
    int cx = ax0 + tid % nx;
    int cy = ay0 + (tid / nx) % ny;
    int cz = az0 + tid / (nx * ny);
    int cc = (cz * GDIM + cy) * GDIM + cx;
    int s0 = cell_start[cc];
    cell_s0_s[tid] = s0;
    len_s[tid] = cell_start[cc + 1] - s0;
  }
  __syncthreads();
  if (tid == 0) {
    int off = 0;
    for (int m = 0; m < nbc; ++m) { pref_s[m] = off; off += len_s[m]; }
    pref_s[nbc] = off;
    nc_s = nbc;
    total_s = off;
  }
  __syncthreads();
  const int nc = nc_s, total = total_s;

  for (int idx = tid; idx < total && idx < CAPC; idx += 256) {
    int c = 0;
    while (c + 1 < nc && pref_s[c + 1] <= idx) ++c;
    int g = cell_s0_s[c] + (idx - pref_s[c]);
    cpos[idx] = sp4[g];
    cidx[idx] = sidx[g];
  }
  __syncthreads();

  const int wave = tid >> 6, lane = tid & 63;

  for (int base = cs + sub * 4; base < ce; base += 16) {
    const int p = base + wave;
    const bool pok = p < ce;
    const int ld = pok ? p : cs;
    const float4 pi = sp4[ld];
    const int orig = sidx[ld];

    if (tid < 4) cnt_s[tid] = 0;
    if (tid < 64) okey_s[tid >> 4][tid & 15] = ~0ULL;
    __syncthreads();

    float v = 3.0e38f;
    for (int idx = lane; idx < total; idx += 64) {
      float4 q;
      if (idx < CAPC) q = cpos[idx];
      else {
        int c = 0;
        while (c + 1 < nc && pref_s[c + 1] <= idx) ++c;
        q = sp4[cell_s0_s[c] + (idx - pref_s[c])];
      }
      v = fminf(v, dist2(pi, q));
    }
    #pragma unroll
    for (int k = 2; k <= 64; k <<= 1) {
      #pragma unroll
      for (int j = k >> 1; j >= 1; j >>= 1) {
        float wv = __shfl_xor(v, j, 64);
        bool dir = (lane & k) != 0;
        bool lower = (lane & j) == 0;
        v = (lower != dir) ? fminf(v, wv) : fmaxf(v, wv);
      }
    }
    const float d16 = __shfl(v, 15, 64);

    if (pok) {
      for (int idx = lane; idx < total; idx += 64) {
        float4 q;
        int qi;
        if (idx < CAPC) { q = cpos[idx]; qi = cidx[idx]; }
        else {
          int c = 0;
          while (c + 1 < nc && pref_s[c + 1] <= idx) ++c;
          int g = cell_s0_s[c] + (idx - pref_s[c]);
          q = sp4[g]; qi = sidx[g];
        }
        float d = dist2(pi, q);
        if (d <= d16) {
          int pos = atomicAdd(&cnt_s[wave], 1);
          if (pos < CAP_H) hk_s[wave][pos] = make_key(d, qi);
        }
      }
    }
    __syncthreads();

    const int cntr = cnt_s[wave];
    const bool overflow = cntr > CAP_H;
    const int cnt = overflow ? 0 : cntr;

    if (pok && lane < cnt) {
      unsigned long long key = hk_s[wave][lane];
      int rk = 0;
      for (int j = 0; j < cnt; ++j) rk += (hk_s[wave][j] < key) ? 1 : 0;
      if (rk < 16) okey_s[wave][rk] = key;
    }
    __syncthreads();

    if (lane == 0 && pok) {
      unsigned long long akm[16];
      if (!overflow) {
        #pragma unroll
        for (int s = 0; s < 16; ++s) akm[s] = okey_s[wave][15 - s];
      } else {
        #pragma unroll
        for (int s = 0; s < 16; ++s) akm[s] = ~0ULL;
        for (int idx = 0; idx < total; ++idx) {
          float4 q; int qi;
          if (idx < CAPC) { q = cpos[idx]; qi = cidx[idx]; }
          else {
            int c = 0;
            while (c + 1 < nc && pref_s[c + 1] <= idx) ++c;
            int g = cell_s0_s[c] + (idx - pref_s[c]);
            q = sp4[g]; qi = sidx[g];
          }
          chain_insert(akm, make_key(dist2(pi, q), qi));
        }
      }
      float r;
      if (akm[0] == ~0ULL) {
        r = 1e9f;
      } else {
        unsigned int ord = (unsigned int)(akm[0] >> 32);
        unsigned int di = (ord & 0x80000000u) ? (ord ^ 0x80000000u) : ~ord;
        float dd = __uint_as_float(di);
        r = sqrtf(fmaxf(dd, 0.f)) * 1.001f + 1e-4f;
      }
      int lx = (int)fminf(fmaxf(floorf((pi.x - r) * GDIM), 0.f), (float)(GDIM - 1));
      int ux = (int)fminf(fmaxf(floorf((pi.x + r) * GDIM), 0.f), (float)(GDIM - 1));
      int ly = (int)fminf(fmaxf(floorf((pi.y - r) * GDIM), 0.f), (float)(GDIM - 1));
      int uy = (int)fminf(fmaxf(floorf((pi.y + r) * GDIM), 0.f), (float)(GDIM - 1));
      int lz = (int)fminf(fmaxf(floorf((pi.z - r) * GDIM), 0.f), (float)(GDIM - 1));
      int uz = (int)fminf(fmaxf(floorf((pi.z + r) * GDIM), 0.f), (float)(GDIM - 1));
      if (lx < ax0 || ux > ax1 || ly < ay0 || uy > ay1 || lz < az0 || uz > az1) {
        for (int cz = lz; cz <= uz; ++cz)
          for (int cy = ly; cy <= uy; ++cy)
            for (int cx = lx; cx <= ux; ++cx) {
              if (cx >= ax0 && cx <= ax1 && cy >= ay0 && cy <= ay1 && cz >= az0 && cz <= az1)
                continue;
              int cc = (cz * GDIM + cy) * GDIM + cx;
              int s0 = cell_start[cc], e0 = cell_start[cc + 1];
              for (int k = s0; k < e0; ++k) {
                float4 q = sp4[k];
                chain_insert(akm, make_key(dist2(pi, q), sidx[k]));
              }
            }
      }
      #pragma unroll
      for (int s = 0; s < 16; ++s) nbr[orig * NSAMP + s] = (int)(akm[s] & 0xFFFFFFFFu);
    }
    __syncthreads();
  }
}

// ---------------------------------------------------------------- fused per-point transform: 2 points/block,
// all-wave MFMA, wave-local stage-6 (no psum LDS, direct coalesced stores)
__global__ __launch_bounds__(256) void fused_pt(
    const float4* __restrict__ sp4, const int* __restrict__ sidx, const int* __restrict__ rank,
    const __hip_bfloat16* __restrict__ xqkv, const int* __restrict__ nbr,
    const float* __restrict__ pw1, const float* __restrict__ pb1,
    const float* __restrict__ pbng, const float* __restrict__ pbnb,
    const float* __restrict__ pbnm, const float* __restrict__ pbnv,
    const float* __restrict__ pw2, const float* __restrict__ pb2,
    const float* __restrict__ sc1, const float* __restrict__ of1,
    const __hip_bfloat16* __restrict__ l1wp, const float* __restrict__ l1b,
    const float* __restrict__ bn2g, const float* __restrict__ bn2b,
    const float* __restrict__ bn2m, const float* __restrict__ bn2v,
    const __hip_bfloat16* __restrict__ l2wp, const float* __restrict__ l2b,
    float* __restrict__ out) {
  __shared__ __align__(16) __hip_bfloat16 a_s[2][NSAMP][264];
  __shared__ __align__(16) __hip_bfloat16 h1_s[2][NSAMP][40];
  __shared__ float w_s[2][NSAMP][33];
  __shared__ float q3_s[2][NSAMP][4];
  __shared__ int jn[2][NSAMP];
  __shared__ int iorig[2];

  const int b0 = blockIdx.x * 2;
  const int tid = threadIdx.x;

  if (tid < 32) {
    int spt = tid >> 4, t = tid & 15;
    int b = b0 + spt;
    int i = sidx[b];
    if (t == 0) iorig[spt] = i;
    int j = nbr[i * NSAMP + t];
    int k = rank[j];
    jn[spt][t] = k;
    float4 pj = sp4[k];
    float4 pc = sp4[b];
    float rx = pj.x - pc.x;
    float ry = pj.y - pc.y;
    float rz = pj.z - pc.z;
    #pragma unroll
    for (int c3 = 0; c3 < 3; ++c3) {
      float t2 = rx * pw1[0 * 3 + c3] + ry * pw1[1 * 3 + c3] + rz * pw1[2 * 3 + c3] + pb1[c3];
      t2 = (t2 - pbnm[c3]) * rsqrtf(pbnv[c3] + EPSBN) * pbng[c3] + pbnb[c3];
      q3_s[spt][t][c3] = fmaxf(t2, 0.f);
    }
  }
  __syncthreads();

  const int pt = tid >> 7;
  const int t127 = tid & 127;
  const int g = t127 >> 5;
  const int cg = (t127 & 31) * 8;   // also == (lane&31)*8 for waves 0/1 in stage 6
  const int b = b0 + pt;

  float xqv[8], s1v[8], o1v[8], w20v[8], w21v[8], w22v[8], pb2v[8];
  {
    bf16x8 xq8 = *(const bf16x8*)&xqkv[(size_t)b * 768 + cg];
    #pragma unroll
    for (int u = 0; u < 8; ++u) {
      int c = cg + u;
      xqv[u] = b2f(xq8[u]);
      s1v[u] = sc1[c];
      o1v[u] = of1[c];
      w20v[u] = pw2[c];
      w21v[u] = pw2[256 + c];
      w22v[u] = pw2[512 + c];
      pb2v[u] = pb2[c];
    }
  }

  // stage 2: gather xk, r_qk, bn1+relu -> a_s (4 passes x 4 groups)
  #pragma unroll
  for (int pass = 0; pass < 4; ++pass) {
    int t = g + pass * 4;
    int k = jn[pt][t];
    float q30 = q3_s[pt][t][0], q31 = q3_s[pt][t][1], q32 = q3_s[pt][t][2];
    bf16x8 xk8 = *(const bf16x8*)&xqkv[(size_t)k * 768 + 256 + cg];
    bf16x8 av;
    #pragma unroll
    for (int u = 0; u < 8; ++u) {
      float prv = q30 * w20v[u] + q31 * w21v[u] + q32 * w22v[u] + pb2v[u];
      float r = b2f(xk8[u]) - xqv[u] + prv;
      av[u] = f2b(fmaxf(r * s1v[u] + o1v[u], 0.f));
    }
    *(bf16x8*)&a_s[pt][t][cg] = av;
  }
  __syncthreads();

  // stage 3: linear_w l1 via MFMA — all 4 waves (wave = mpt*2 + hh)
  const int w = tid >> 6;
  const int lane = tid & 63;
  const int mpt = w >> 1, hh = w & 1;
  const int nn = lane & 15, q = lane >> 4;
  {
    f32x4 acc = {0.f, 0.f, 0.f, 0.f};
    #pragma unroll
    for (int k0 = 0; k0 < 256; k0 += 32) {
      bf16x8 a = *(const bf16x8*)&a_s[mpt][nn][k0 + q * 8];
      bf16x8 bb = *(const bf16x8*)&l1wp[hh * 4096 + (k0 >> 3) * 128 + q * 128 + nn * 8];
      acc = __builtin_amdgcn_mfma_f32_16x16x32_bf16(a, bb, acc, 0, 0, 0);
    }
    int h = hh * 16 + nn;
    float s2 = bn2g[h] * rsqrtf(bn2v[h] + EPSBN);
    float o2 = bn2b[h] - bn2m[h] * s2;
    float l1bh = l1b[h];
    #pragma unroll
    for (int r = 0; r < 4; ++r)
      h1_s[mpt][q * 4 + r][h] = __float2bfloat16(fmaxf((acc[r] + l1bh) * s2 + o2, 0.f));
  }
  __syncthreads();

  // stage 4: linear_w l2 via MFMA — all 4 waves
  {
    bf16x8 a = *(const bf16x8*)&h1_s[mpt][nn][q * 8];
    bf16x8 bb = *(const bf16x8*)&l2wp[hh * 512 + q * 128 + nn * 8];
    f32x4 z = {0.f, 0.f, 0.f, 0.f};
    f32x4 d = __builtin_amdgcn_mfma_f32_16x16x32_bf16(a, bb, z, 0, 0, 0);
    int h = hh * 16 + nn;
    float l2bh = l2b[h];
    #pragma unroll
    for (int r = 0; r < 4; ++r) w_s[mpt][q * 4 + r][h] = d[r] + l2bh;
  }
  __syncthreads();

  // stage 5: softmax over neighbors (64 threads: 2 pts x 32 h)
  if (tid < 64) {
    int spt = tid >> 5, h = tid & 31;
    float m = -1e30f;
    #pragma unroll
    for (int t = 0; t < NSAMP; ++t) m = fmaxf(m, w_s[spt][t][h]);
    float e[NSAMP];
    float ssum = 0.f;
    #pragma unroll
    for (int t = 0; t < NSAMP; ++t) { e[t] = __expf(w_s[spt][t][h] - m); ssum += e[t]; }
    float inv = 1.f / ssum;
    #pragma unroll
    for (int t = 0; t < NSAMP; ++t) w_s[spt][t][h] = e[t] * inv;
  }
  __syncthreads();

  // stage 6: one wave per point (waves 0,1), 2 groups x 8 passes;
  // channel constants are channel-only, so registers stay valid.
  if (w < 2) {
    const int spt = w;
    const int gg = lane >> 5;
    const int hb = cg & 31;
    float acc8[8];
    #pragma unroll
    for (int u = 0; u < 8; ++u) acc8[u] = 0.f;
    #pragma unroll
    for (int pass = 0; pass < 8; ++pass) {
      int t = gg + pass * 2;
      int k = jn[spt][t];
      float q30 = q3_s[spt][t][0], q31 = q3_s[spt][t][1], q32 = q3_s[spt][t][2];
      bf16x8 xv8 = *(const bf16x8*)&xqkv[(size_t)k * 768 + 512 + cg];
      #pragma unroll
      for (int u = 0; u < 8; ++u) {
        float prv = q30 * w20v[u] + q31 * w21v[u] + q32 * w22v[u] + pb2v[u];
        acc8[u] += (b2f(xv8[u]) + prv) * w_s[spt][t][hb + u];
      }
    }
    #pragma unroll
    for (int u = 0; u < 8; ++u) acc8[u] += __shfl_xor(acc8[u], 32, 64);
    if (lane < 32) {
      int io = iorig[spt];
      float4 v0 = make_float4(acc8[0], acc8[1], acc8[2], acc8[3]);
      float4 v1 = make_float4(acc8[4], acc8[5], acc8[6], acc8[7]);
      *(float4*)&out[(size_t)io * OUT_C + cg] = v0;
      *(float4*)&out[(size_t)io * OUT_C + cg + 4] = v1;
    }
  }
}

// ---------------------------------------------------------------- launch
extern "C" void kernel_launch(void* const* d_in, const int* in_sizes, int n_in,
                              void* d_out, int out_size, void* d_ws, size_t ws_size,
                              hipStream_t stream) {
  const float* p    = (const float*)d_in[0];
  const float* x    = (const float*)d_in[1];
  const float* wq   = (const float*)d_in[2];
  const float* bq   = (const float*)d_in[3];
  const float* wk   = (const float*)d_in[4];
  const float* bk   = (const float*)d_in[5];
  const float* wv   = (const float*)d_in[6];
  const float* bv   = (const float*)d_in[7];
  const float* pw1  = (const float*)d_in[8];
  const float* pb1  = (const float*)d_in[9];
  const float* pbng = (const float*)d_in[10];
  const float* pbnb = (const float*)d_in[11];
  const float* pbnm = (const float*)d_in[12];
  const float* pbnv = (const float*)d_in[13];
  const float* pw2  = (const float*)d_in[14];
  const float* pb2  = (const float*)d_in[15];
  const float* bn1g = (const float*)d_in[16];
  const float* bn1b = (const float*)d_in[17];
  const float* bn1m = (const float*)d_in[18];
  const float* bn1v = (const float*)d_in[19];
  const float* l1w  = (const float*)d_in[20];
  const float* l1b  = (const float*)d_in[21];
  const float* bn2g = (const float*)d_in[22];
  const float* bn2b = (const float*)d_in[23];
  const float* bn2m = (const float*)d_in[24];
  const float* bn2v = (const float*)d_in[25];
  const float* l2w  = (const float*)d_in[26];
  const float* l2b  = (const float*)d_in[27];
  float* out = (float*)d_out;

  char* ws = (char*)d_ws;
  float4* p4       = (float4*)(ws + 0x000000);
  float*  biasp    = (float*)(ws + 0x040000);
  int*    cursor   = (int*)(ws + 0x042800);
  int*    cell_st  = (int*)(ws + 0x043000);
  int*    pt_cell  = (int*)(ws + 0x044000);
  float4* sp4      = (float4*)(ws + 0x050000);
  int*    sidx     = (int*)(ws + 0x070000);
  __hip_bfloat16* l1wp = (__hip_bfloat16*)(ws + 0x080000);
  __hip_bfloat16* l2wp = (__hip_bfloat16*)(ws + 0x084000);
  float*  sc1      = (float*)(ws + 0x085000);
  float*  of1      = (float*)(ws + 0x085800);
  int*    rank     = (int*)(ws + 0x088000);
  int*    nbr      = (int*)(ws + 0x090000);
  __hip_bfloat16* Bp   = (__hip_bfloat16*)(ws + 0x110000);
  __hip_bfloat16* xqkv = (__hip_bfloat16*)(ws + 0x570000);

  prep_kernel<<<dim3(768), dim3(256), 0, stream>>>(
      p, wq, wk, wv, bq, bk, bv, l1w, l2w, bn1g, bn1b, bn1m, bn1v,
      p4, Bp, biasp, l1wp, l2wp, sc1, of1, cursor, pt_cell);
  scatter_scan<<<dim3(16), dim3(512), 0, stream>>>(
      p4, pt_cell, cell_st, cursor, sp4, sidx, rank);
  knn_grid<<<dim3(NCELL * 4), dim3(256), 0, stream>>>(sp4, sidx, cell_st, nbr);
  gemm_qkv_mfma<<<dim3(768), dim3(256), 0, stream>>>(x, sidx, Bp, biasp, xqkv);
  fused_pt<<<dim3(N_PTS / 2), dim3(256), 0, stream>>>(
      sp4, sidx, rank, xqkv, nbr, pw1, pb1, pbng, pbnb, pbnm, pbnv, pw2, pb2,
      sc1, of1, l1wp, l1b, bn2g, bn2b, bn2m, bn2v, l2wp, l2b, out);
}

// Round 16
// 202.851 us; speedup vs baseline: 1.0464x; 1.0464x over previous
//
#include <hip/hip_runtime.h>
#include <hip/hip_bf16.h>
#include <math.h>

#define N_PTS 8192
#define C_IN  256
#define OUT_C 256
#define NSAMP 16
#define H_W   32
#define EPSBN 1e-5f
#define GDIM  8
#define NCELL (GDIM * GDIM * GDIM)
#define CAPC  768
#define CAP_H 64

typedef short bf16x8 __attribute__((ext_vector_type(8)));
typedef float f32x4  __attribute__((ext_vector_type(4)));

// EXACT arithmetic from the passing rounds: plain expression, default
// compiler contraction, shared by all scans. Do NOT change the rounding.
__device__ __forceinline__ float dist2(const float4 a, const float4 b) {
  float dot = a.x * b.x + a.y * b.y + a.z * b.z;
  return a.w + b.w - 2.0f * dot;
}

__device__ __forceinline__ unsigned long long make_key(float d, int j) {
  unsigned int di = __float_as_uint(d);
  unsigned int ord = ((int)di >= 0) ? (di ^ 0x80000000u) : ~di;
  return ((unsigned long long)ord << 32) | (unsigned int)j;
}

__device__ __forceinline__ void chain_insert(unsigned long long (&ak)[16], unsigned long long key) {
  if (key < ak[0]) {
    #pragma unroll
    for (int s = 0; s < 15; ++s) {
      unsigned long long mn = ak[s] < key ? ak[s] : key;
      unsigned long long nx = ak[s + 1];
      ak[s] = nx > mn ? nx : mn;
    }
    ak[15] = ak[15] < key ? ak[15] : key;
  }
}

// bf16 bit helpers (same rounding as __float2bfloat16 / widening as HW)
__device__ __forceinline__ float b2f(short s) {
  return __uint_as_float(((unsigned int)(unsigned short)s) << 16);
}
__device__ __forceinline__ short f2b(float v) {
  __hip_bfloat16 h = __float2bfloat16(v);
  short s;
  __builtin_memcpy(&s, &h, 2);
  return s;
}

// ---------------------------------------------------------------- prep
__global__ __launch_bounds__(256) void prep_kernel(
    const float* __restrict__ p,
    const float* __restrict__ wq, const float* __restrict__ wk, const float* __restrict__ wv,
    const float* __restrict__ bq, const float* __restrict__ bk, const float* __restrict__ bv,
    const float* __restrict__ l1w, const float* __restrict__ l2w,
    const float* __restrict__ bn1g, const float* __restrict__ bn1b,
    const float* __restrict__ bn1m, const float* __restrict__ bn1v,
    float4* __restrict__ p4, __hip_bfloat16* __restrict__ Bp, float* __restrict__ biasp,
    __hip_bfloat16* __restrict__ l1wp, __hip_bfloat16* __restrict__ l2wp,
    float* __restrict__ sc1, float* __restrict__ of1,
    int* __restrict__ cursor, int* __restrict__ pt_cell) {
  int tid = blockIdx.x * blockDim.x + threadIdx.x;
  if (tid < 48 * 32 * 16 * 8) {
    int kj = tid & 7, n = (tid >> 3) & 15, kb = (tid >> 7) & 31, nt = tid >> 12;
    int k = kb * 8 + kj, col = nt * 16 + n;
    float v;
    if (col < 256)      v = wq[k * 256 + col];
    else if (col < 512) v = wk[k * 256 + (col - 256)];
    else                v = wv[k * 256 + (col - 512)];
    Bp[tid] = __float2bfloat16(v);
  }
  if (tid < 768) {
    biasp[tid] = tid < 256 ? bq[tid] : (tid < 512 ? bk[tid - 256] : bv[tid - 512]);
  }
  if (tid < 8192) {
    int kj = tid & 7, n = (tid >> 3) & 15, kb = (tid >> 7) & 31, nt = (tid >> 12) & 1;
    int k = kb * 8 + kj, col = nt * 16 + n;
    l1wp[tid] = __float2bfloat16(l1w[k * 32 + col]);
  }
  if (tid < 1024) {
    int kj = tid & 7, n = (tid >> 3) & 15, kb = (tid >> 7) & 3, nt = (tid >> 9) & 1;
    int k = kb * 8 + kj, col = nt * 16 + n;
    l2wp[tid] = __float2bfloat16(l2w[k * 32 + col]);
  }
  if (tid < 256) {
    float s1 = bn1g[tid] * rsqrtf(bn1v[tid] + EPSBN);
    sc1[tid] = s1;
    of1[tid] = bn1b[tid] - bn1m[tid] * s1;
  }
  if (tid < NCELL) cursor[tid] = 0;
  if (tid < N_PTS) {
    float px = p[tid * 3 + 0], py = p[tid * 3 + 1], pz = p[tid * 3 + 2];
    float sq = px * px;
    sq += py * py;
    sq += pz * pz;
    p4[tid] = make_float4(px, py, pz, sq);
    int cx = min(GDIM - 1, max(0, (int)(px * GDIM)));
    int cy = min(GDIM - 1, max(0, (int)(py * GDIM)));
    int cz = min(GDIM - 1, max(0, (int)(pz * GDIM)));
    pt_cell[tid] = (cz * GDIM + cy) * GDIM + cx;
  }
}

// ---------------------------------------------------------------- scatter: in-block LDS histogram + scan + scatter
__global__ __launch_bounds__(512) void scatter_scan(
    const float4* __restrict__ p4, const int* __restrict__ pt_cell,
    int* __restrict__ cell_start, int* __restrict__ cursor,
    float4* __restrict__ sp4, int* __restrict__ sidx, int* __restrict__ rank) {
  __shared__ int buf[NCELL];
  const int t = threadIdx.x;
  buf[t] = 0;
  __syncthreads();
  for (int i = t; i < N_PTS; i += 512) atomicAdd(&buf[pt_cell[i]], 1);
  __syncthreads();
  for (int off = 1; off < NCELL; off <<= 1) {
    int add = (t >= off) ? buf[t - off] : 0;
    __syncthreads();
    buf[t] += add;
    __syncthreads();
  }
  if (blockIdx.x == 0) {
    cell_start[t + 1] = buf[t];
    if (t == 0) cell_start[0] = 0;
  }
  const int pid = blockIdx.x * 512 + t;
  const int c = pt_cell[pid];
  const int start = (c == 0) ? 0 : buf[c - 1];
  const int pos = start + atomicAdd(&cursor[c], 1);
  sp4[pos] = p4[pid];
  sidx[pos] = pid;
  rank[pid] = pos;
}

// ---------------------------------------------------------------- qkv gemm: bf16 MFMA, A gathered from fp32 x via sidx
__global__ __launch_bounds__(256) void gemm_qkv_mfma(
    const float* __restrict__ x, const int* __restrict__ sidx,
    const __hip_bfloat16* __restrict__ Bp,
    const float* __restrict__ biasp, __hip_bfloat16* __restrict__ xqkv) {
  const int w = threadIdx.x >> 6;
  const int lane = threadIdx.x & 63;
  const int gw = blockIdx.x * 4 + w;
  const int m0 = (gw & 127) * 64;
  const int nt4 = (gw >> 7) * 4;
  const int n = lane & 15, q = lane >> 4;

  int o[4];
  #pragma unroll
  for (int mi = 0; mi < 4; ++mi) o[mi] = sidx[m0 + mi * 16 + n];

  f32x4 acc[4][4];
  #pragma unroll
  for (int mi = 0; mi < 4; ++mi)
    #pragma unroll
    for (int ni = 0; ni < 4; ++ni) acc[mi][ni] = (f32x4){0.f, 0.f, 0.f, 0.f};

  for (int k0 = 0; k0 < 256; k0 += 32) {
    bf16x8 af[4], bfr[4];
    #pragma unroll
    for (int mi = 0; mi < 4; ++mi) {
      const float* xr = &x[(size_t)o[mi] * 256 + k0 + q * 8];
      float4 xa = *(const float4*)xr;
      float4 xb = *(const float4*)(xr + 4);
      af[mi][0] = f2b(xa.x); af[mi][1] = f2b(xa.y);
      af[mi][2] = f2b(xa.z); af[mi][3] = f2b(xa.w);
      af[mi][4] = f2b(xb.x); af[mi][5] = f2b(xb.y);
      af[mi][6] = f2b(xb.z); af[mi][7] = f2b(xb.w);
    }
    #pragma unroll
    for (int ni = 0; ni < 4; ++ni)
      bfr[ni] = *(const bf16x8*)&Bp[(size_t)(nt4 + ni) * 4096 + (k0 >> 3) * 128 + q * 128 + n * 8];
    #pragma unroll
    for (int mi = 0; mi < 4; ++mi)
      #pragma unroll
      for (int ni = 0; ni < 4; ++ni)
        acc[mi][ni] = __builtin_amdgcn_mfma_f32_16x16x32_bf16(af[mi], bfr[ni], acc[mi][ni], 0, 0, 0);
  }
  #pragma unroll
  for (int ni = 0; ni < 4; ++ni) {
    int col = (nt4 + ni) * 16 + n;
    float b = biasp[col];
    #pragma unroll
    for (int mi = 0; mi < 4; ++mi)
      #pragma unroll
      for (int r = 0; r < 4; ++r)
        xqkv[(size_t)(m0 + mi * 16 + q * 4 + r) * 768 + col] = __float2bfloat16(acc[mi][ni][r] + b);
  }
}

// ---------------------------------------------------------------- exact grid KNN v5:
// per-slice top-2 -> LDS rank -> threshold u16 (>= d16, data-derived) ->
// collect -> exact u64 rank-select. Fallbacks exact.
__global__ __launch_bounds__(256) void knn_grid(
    const float4* __restrict__ sp4, const int* __restrict__ sidx,
    const int* __restrict__ cell_start, int* __restrict__ nbr) {
  __shared__ float4 cpos[CAPC];
  __shared__ int    cidx[CAPC];
  __shared__ unsigned long long hk_s[8][CAP_H];
  __shared__ unsigned long long okey_s[8][16];
  __shared__ float tv_s[8][64];
  __shared__ int cnt_s[8];
  __shared__ int cell_s0_s[27];
  __shared__ int len_s[27];
  __shared__ int pref_s[28];
  __shared__ int nc_s, total_s;

  const int cell = blockIdx.x >> 1;
  const int sub  = blockIdx.x & 1;
  const int tid = threadIdx.x;
  const int hcx = cell & 7, hcy = (cell >> 3) & 7, hcz = cell >> 6;
  const int cs = cell_start[cell], ce = cell_start[cell + 1];

  const int ax0 = max(hcx - 1, 0), ax1 = min(hcx + 1, GDIM - 1);
  const int ay0 = max(hcy - 1, 0), ay1 = min(hcy + 1, GDIM - 1);
  const int az0 = max(hcz - 1, 0), az1 = min(hcz + 1, GDIM - 1);
  const int nx = ax1 - ax0 + 1, ny = ay1 - ay0 + 1, nz = az1 - az0 + 1;
  const int nbc = nx * ny * nz;

  if (tid < nbc) {
    int cx = ax0 + tid % nx;
    int cy = ay0 + (tid / nx) % ny;
    int cz = az0 + tid / (nx * ny);
    int cc = (cz * GDIM + cy) * GDIM + cx;
    int s0 = cell_start[cc];
    cell_s0_s[tid] = s0;
    len_s[tid] = cell_start[cc + 1] - s0;
  }
  __syncthreads();
  if (tid == 0) {
    int off = 0;
    for (int m = 0; m < nbc; ++m) { pref_s[m] = off; off += len_s[m]; }
    pref_s[nbc] = off;
    nc_s = nbc;
    total_s = off;
  }
  __syncthreads();
  const int nc = nc_s, total = total_s;

  for (int idx = tid; idx < total && idx < CAPC; idx += 256) {
    int c = 0;
    while (c + 1 < nc && pref_s[c + 1] <= idx) ++c;
    int g = cell_s0_s[c] + (idx - pref_s[c]);
    cpos[idx] = sp4[g];
    cidx[idx] = sidx[g];
  }
  __syncthreads();

  const int ptl = tid >> 5, slice = tid & 31;

  for (int p0 = cs + 8 * sub; p0 < ce; p0 += 16) {
    const int np = min(8, ce - p0);
    const bool pok = ptl < np;
    const int ld = pok ? (p0 + ptl) : cs;
    const float4 pi = sp4[ld];
    const int orig = sidx[ld];

    if (tid < 8) cnt_s[tid] = 0;
    if (tid < 128) okey_s[tid >> 4][tid & 15] = ~0ULL;
    __syncthreads();

    // phase 1: per-slice 2 smallest distances (no chains, no merges)
    float t0 = 3.0e38f, t1 = 3.0e38f;  // t0 <= t1
    for (int idx = slice; idx < total; idx += 32) {
      float4 q;
      if (idx < CAPC) q = cpos[idx];
      else {
        int c = 0;
        while (c + 1 < nc && pref_s[c + 1] <= idx) ++c;
        q = sp4[cell_s0_s[c] + (idx - pref_s[c])];
      }
      float d = dist2(pi, q);
      if (d < t1) {
        if (d < t0) { t1 = t0; t0 = d; } else { t1 = d; }
      }
    }
    tv_s[ptl][slice * 2]     = t0;
    tv_s[ptl][slice * 2 + 1] = t1;
    __syncthreads();

    // 16th-smallest of the 64-value union via strict-rank (broadcast reads)
    int r0 = 0, r1 = 0;
    #pragma unroll 8
    for (int j = 0; j < 64; ++j) {
      float wv = tv_s[ptl][j];
      r0 += (wv < t0) ? 1 : 0;
      r1 += (wv < t1) ? 1 : 0;
    }
    float cand = fmaxf(r0 <= 15 ? t0 : -3.0e38f, r1 <= 15 ? t1 : -3.0e38f);
    cand = fmaxf(cand, __shfl_xor(cand, 1, 64));
    cand = fmaxf(cand, __shfl_xor(cand, 2, 64));
    cand = fmaxf(cand, __shfl_xor(cand, 4, 64));
    cand = fmaxf(cand, __shfl_xor(cand, 8, 64));
    cand = fmaxf(cand, __shfl_xor(cand, 16, 64));
    const float d16 = cand;   // >= true d16; #(d<=d16) >= 16 when total>=16

    // phase 2: threshold collect of (dist, idx) keys
    if (pok) {
      for (int idx = slice; idx < total; idx += 32) {
        float4 q;
        int qi;
        if (idx < CAPC) { q = cpos[idx]; qi = cidx[idx]; }
        else {
          int c = 0;
          while (c + 1 < nc && pref_s[c + 1] <= idx) ++c;
          int g = cell_s0_s[c] + (idx - pref_s[c]);
          q = sp4[g]; qi = sidx[g];
        }
        float d = dist2(pi, q);
        if (d <= d16) {
          int pos = atomicAdd(&cnt_s[ptl], 1);
          if (pos < CAP_H) hk_s[ptl][pos] = make_key(d, qi);
        }
      }
    }
    __syncthreads();

    const int cntr = cnt_s[ptl];
    const bool overflow = cntr > CAP_H;   // needs 65+ candidates <= u16 (~never)
    const int cnt = overflow ? 0 : cntr;

    // exact rank-select of top-16 among collected keys
    if (pok) {
      for (int i = slice; i < cnt; i += 32) {
        unsigned long long key = hk_s[ptl][i];
        int rk = 0;
        for (int j = 0; j < cnt; ++j) rk += (hk_s[ptl][j] < key) ? 1 : 0;
        if (rk < 16) okey_s[ptl][rk] = key;
      }
    }
    __syncthreads();

    if (slice == 0 && pok) {
      unsigned long long akm[16];
      if (!overflow) {
        #pragma unroll
        for (int s = 0; s < 16; ++s) akm[s] = okey_s[ptl][15 - s];
      } else {
        #pragma unroll
        for (int s = 0; s < 16; ++s) akm[s] = ~0ULL;
        for (int idx = 0; idx < total; ++idx) {
          float4 q; int qi;
          if (idx < CAPC) { q = cpos[idx]; qi = cidx[idx]; }
          else {
            int c = 0;
            while (c + 1 < nc && pref_s[c + 1] <= idx) ++c;
            int g = cell_s0_s[c] + (idx - pref_s[c]);
            q = sp4[g]; qi = sidx[g];
          }
          chain_insert(akm, make_key(dist2(pi, q), qi));
        }
      }
      // phase B: ball-vs-clamped-box exactness guard
      float r;
      if (akm[0] == ~0ULL) {
        r = 1e9f;
      } else {
        unsigned int ord = (unsigned int)(akm[0] >> 32);
        unsigned int di = (ord & 0x80000000u) ? (ord ^ 0x80000000u) : ~ord;
        float dd = __uint_as_float(di);
        r = sqrtf(fmaxf(dd, 0.f)) * 1.001f + 1e-4f;
      }
      int lx = (int)fminf(fmaxf(floorf((pi.x - r) * GDIM), 0.f), (float)(GDIM - 1));
      int ux = (int)fminf(fmaxf(floorf((pi.x + r) * GDIM), 0.f), (float)(GDIM - 1));
      int ly = (int)fminf(fmaxf(floorf((pi.y - r) * GDIM), 0.f), (float)(GDIM - 1));
      int uy = (int)fminf(fmaxf(floorf((pi.y + r) * GDIM), 0.f), (float)(GDIM - 1));
      int lz = (int)fminf(fmaxf(floorf((pi.z - r) * GDIM), 0.f), (float)(GDIM - 1));
      int uz = (int)fminf(fmaxf(floorf((pi.z + r) * GDIM), 0.f), (float)(GDIM - 1));
      if (lx < ax0 || ux > ax1 || ly < ay0 || uy > ay1 || lz < az0 || uz > az1) {
        for (int cz = lz; cz <= uz; ++cz)
          for (int cy = ly; cy <= uy; ++cy)
            for (int cx = lx; cx <= ux; ++cx) {
              if (cx >= ax0 && cx <= ax1 && cy >= ay0 && cy <= ay1 && cz >= az0 && cz <= az1)
                continue;
              int cc = (cz * GDIM + cy) * GDIM + cx;
              int s0 = cell_start[cc], e0 = cell_start[cc + 1];
              for (int k = s0; k < e0; ++k) {
                float4 q = sp4[k];
                chain_insert(akm, make_key(dist2(pi, q), sidx[k]));
              }
            }
      }
      #pragma unroll
      for (int s = 0; s < 16; ++s) nbr[orig * NSAMP + s] = (int)(akm[s] & 0xFFFFFFFFu);
    }
    __syncthreads();
  }
}

// ---------------------------------------------------------------- fused per-point transform: 2 points/block, all-wave MFMA
__global__ __launch_bounds__(256) void fused_pt(
    const float4* __restrict__ sp4, const int* __restrict__ sidx, const int* __restrict__ rank,
    const __hip_bfloat16* __restrict__ xqkv, const int* __restrict__ nbr,
    const float* __restrict__ pw1, const float* __restrict__ pb1,
    const float* __restrict__ pbng, const float* __restrict__ pbnb,
    const float* __restrict__ pbnm, const float* __restrict__ pbnv,
    const float* __restrict__ pw2, const float* __restrict__ pb2,
    const float* __restrict__ sc1, const float* __restrict__ of1,
    const __hip_bfloat16* __restrict__ l1wp, const float* __restrict__ l1b,
    const float* __restrict__ bn2g, const float* __restrict__ bn2b,
    const float* __restrict__ bn2m, const float* __restrict__ bn2v,
    const __hip_bfloat16* __restrict__ l2wp, const float* __restrict__ l2b,
    float* __restrict__ out) {
  __shared__ __align__(16) __hip_bfloat16 a_s[2][NSAMP][264];
  __shared__ __align__(16) __hip_bfloat16 h1_s[2][NSAMP][40];
  __shared__ float w_s[2][NSAMP][33];
  __shared__ float q3_s[2][NSAMP][4];
  __shared__ int jn[2][NSAMP];
  __shared__ float psum[2][2][264];
  __shared__ int iorig[2];

  const int b0 = blockIdx.x * 2;
  const int tid = threadIdx.x;

  if (tid < 32) {
    int spt = tid >> 4, t = tid & 15;
    int b = b0 + spt;
    int i = sidx[b];
    if (t == 0) iorig[spt] = i;
    int j = nbr[i * NSAMP + t];
    int k = rank[j];
    jn[spt][t] = k;
    float4 pj = sp4[k];
    float4 pc = sp4[b];
    float rx = pj.x - pc.x;
    float ry = pj.y - pc.y;
    float rz = pj.z - pc.z;
    #pragma unroll
    for (int c3 = 0; c3 < 3; ++c3) {
      float t2 = rx * pw1[0 * 3 + c3] + ry * pw1[1 * 3 + c3] + rz * pw1[2 * 3 + c3] + pb1[c3];
      t2 = (t2 - pbnm[c3]) * rsqrtf(pbnv[c3] + EPSBN) * pbng[c3] + pbnb[c3];
      q3_s[spt][t][c3] = fmaxf(t2, 0.f);
    }
  }
  __syncthreads();

  const int pt = tid >> 7;
  const int t127 = tid & 127;
  const int g = t127 >> 5;
  const int cg = (t127 & 31) * 8;
  const int b = b0 + pt;

  float xqv[8], s1v[8], o1v[8], w20v[8], w21v[8], w22v[8], pb2v[8];
  {
    bf16x8 xq8 = *(const bf16x8*)&xqkv[(size_t)b * 768 + cg];
    #pragma unroll
    for (int u = 0; u < 8; ++u) {
      int c = cg + u;
      xqv[u] = b2f(xq8[u]);
      s1v[u] = sc1[c];
      o1v[u] = of1[c];
      w20v[u] = pw2[c];
      w21v[u] = pw2[256 + c];
      w22v[u] = pw2[512 + c];
      pb2v[u] = pb2[c];
    }
  }

  #pragma unroll
  for (int pass = 0; pass < 4; ++pass) {
    int t = g + pass * 4;
    int k = jn[pt][t];
    float q30 = q3_s[pt][t][0], q31 = q3_s[pt][t][1], q32 = q3_s[pt][t][2];
    bf16x8 xk8 = *(const bf16x8*)&xqkv[(size_t)k * 768 + 256 + cg];
    bf16x8 av;
    #pragma unroll
    for (int u = 0; u < 8; ++u) {
      float prv = q30 * w20v[u] + q31 * w21v[u] + q32 * w22v[u] + pb2v[u];
      float r = b2f(xk8[u]) - xqv[u] + prv;
      av[u] = f2b(fmaxf(r * s1v[u] + o1v[u], 0.f));
    }
    *(bf16x8*)&a_s[pt][t][cg] = av;
  }
  __syncthreads();

  const int w = tid >> 6;
  const int lane = tid & 63;
  const int mpt = w >> 1, hh = w & 1;
  const int nn = lane & 15, q = lane >> 4;
  {
    f32x4 acc = {0.f, 0.f, 0.f, 0.f};
    #pragma unroll
    for (int k0 = 0; k0 < 256; k0 += 32) {
      bf16x8 a = *(const bf16x8*)&a_s[mpt][nn][k0 + q * 8];
      bf16x8 bb = *(const bf16x8*)&l1wp[hh * 4096 + (k0 >> 3) * 128 + q * 128 + nn * 8];
      acc = __builtin_amdgcn_mfma_f32_16x16x32_bf16(a, bb, acc, 0, 0, 0);
    }
    int h = hh * 16 + nn;
    float s2 = bn2g[h] * rsqrtf(bn2v[h] + EPSBN);
    float o2 = bn2b[h] - bn2m[h] * s2;
    float l1bh = l1b[h];
    #pragma unroll
    for (int r = 0; r < 4; ++r)
      h1_s[mpt][q * 4 + r][h] = __float2bfloat16(fmaxf((acc[r] + l1bh) * s2 + o2, 0.f));
  }
  __syncthreads();

  {
    bf16x8 a = *(const bf16x8*)&h1_s[mpt][nn][q * 8];
    bf16x8 bb = *(const bf16x8*)&l2wp[hh * 512 + q * 128 + nn * 8];
    f32x4 z = {0.f, 0.f, 0.f, 0.f};
    f32x4 d = __builtin_amdgcn_mfma_f32_16x16x32_bf16(a, bb, z, 0, 0, 0);
    int h = hh * 16 + nn;
    float l2bh = l2b[h];
    #pragma unroll
    for (int r = 0; r < 4; ++r) w_s[mpt][q * 4 + r][h] = d[r] + l2bh;
  }
  __syncthreads();

  if (tid < 64) {
    int spt = tid >> 5, h = tid & 31;
    float m = -1e30f;
    #pragma unroll
    for (int t = 0; t < NSAMP; ++t) m = fmaxf(m, w_s[spt][t][h]);
    float e[NSAMP];
    float ssum = 0.f;
    #pragma unroll
    for (int t = 0; t < NSAMP; ++t) { e[t] = __expf(w_s[spt][t][h] - m); ssum += e[t]; }
    float inv = 1.f / ssum;
    #pragma unroll
    for (int t = 0; t < NSAMP; ++t) w_s[spt][t][h] = e[t] * inv;
  }
  __syncthreads();

  const int hb = cg & 31;
  float acc8[8];
  #pragma unroll
  for (int u = 0; u < 8; ++u) acc8[u] = 0.f;
  #pragma unroll
  for (int pass = 0; pass < 4; ++pass) {
    int t = g + pass * 4;
    int k = jn[pt][t];
    float q30 = q3_s[pt][t][0], q31 = q3_s[pt][t][1], q32 = q3_s[pt][t][2];
    bf16x8 xv8 = *(const bf16x8*)&xqkv[(size_t)k * 768 + 512 + cg];
    #pragma unroll
    for (int u = 0; u < 8; ++u) {
      float prv = q30 * w20v[u] + q31 * w21v[u] + q32 * w22v[u] + pb2v[u];
      acc8[u] += (b2f(xv8[u]) + prv) * w_s[pt][t][hb + u];
    }
  }
  #pragma unroll
  for (int u = 0; u < 8; ++u) acc8[u] += __shfl_xor(acc8[u], 32, 64);
  if ((lane >> 5) == 0) {
    #pragma unroll
    for (int u = 0; u < 8; ++u) psum[mpt][hh][cg + u] = acc8[u];
  }
  __syncthreads();
  {
    int opt = tid >> 7;
    int c0 = (tid & 127) * 2;
    float v0 = psum[opt][0][c0] + psum[opt][1][c0];
    float v1 = psum[opt][0][c0 + 1] + psum[opt][1][c0 + 1];
    int io = iorig[opt];
    *(float2*)&out[(size_t)io * OUT_C + c0] = make_float2(v0, v1);
  }
}

// ---------------------------------------------------------------- launch
extern "C" void kernel_launch(void* const* d_in, const int* in_sizes, int n_in,
                              void* d_out, int out_size, void* d_ws, size_t ws_size,
                              hipStream_t stream) {
  const float* p    = (const float*)d_in[0];
  const float* x    = (const float*)d_in[1];
  const float* wq   = (const float*)d_in[2];
  const float* bq   = (const float*)d_in[3];
  const float* wk   = (const float*)d_in[4];
  const float* bk   = (const float*)d_in[5];
  const float* wv   = (const float*)d_in[6];
  const float* bv   = (const float*)d_in[7];
  const float* pw1  = (const float*)d_in[8];
  const float* pb1  = (const float*)d_in[9];
  const float* pbng = (const float*)d_in[10];
  const float* pbnb = (const float*)d_in[11];
  const float* pbnm = (const float*)d_in[12];
  const float* pbnv = (const float*)d_in[13];
  const float* pw2  = (const float*)d_in[14];
  const float* pb2  = (const float*)d_in[15];
  const float* bn1g = (const float*)d_in[16];
  const float* bn1b = (const float*)d_in[17];
  const float* bn1m = (const float*)d_in[18];
  const float* bn1v = (const float*)d_in[19];
  const float* l1w  = (const float*)d_in[20];
  const float* l1b  = (const float*)d_in[21];
  const float* bn2g = (const float*)d_in[22];
  const float* bn2b = (const float*)d_in[23];
  const float* bn2m = (const float*)d_in[24];
  const float* bn2v = (const float*)d_in[25];
  const float* l2w  = (const float*)d_in[26];
  const float* l2b  = (const float*)d_in[27];
  float* out = (float*)d_out;

  char* ws = (char*)d_ws;
  float4* p4       = (float4*)(ws + 0x000000);
  float*  biasp    = (float*)(ws + 0x040000);
  int*    cursor   = (int*)(ws + 0x042800);
  int*    cell_st  = (int*)(ws + 0x043000);
  int*    pt_cell  = (int*)(ws + 0x044000);
  float4* sp4      = (float4*)(ws + 0x050000);
  int*    sidx     = (int*)(ws + 0x070000);
  __hip_bfloat16* l1wp = (__hip_bfloat16*)(ws + 0x080000);
  __hip_bfloat16* l2wp = (__hip_bfloat16*)(ws + 0x084000);
  float*  sc1      = (float*)(ws + 0x085000);
  float*  of1      = (float*)(ws + 0x085800);
  int*    rank     = (int*)(ws + 0x088000);
  int*    nbr      = (int*)(ws + 0x090000);
  __hip_bfloat16* Bp   = (__hip_bfloat16*)(ws + 0x110000);
  __hip_bfloat16* xqkv = (__hip_bfloat16*)(ws + 0x570000);

  prep_kernel<<<dim3(768), dim3(256), 0, stream>>>(
      p, wq, wk, wv, bq, bk, bv, l1w, l2w, bn1g, bn1b, bn1m, bn1v,
      p4, Bp, biasp, l1wp, l2wp, sc1, of1, cursor, pt_cell);
  scatter_scan<<<dim3(16), dim3(512), 0, stream>>>(
      p4, pt_cell, cell_st, cursor, sp4, sidx, rank);
  knn_grid<<<dim3(NCELL * 2), dim3(256), 0, stream>>>(sp4, sidx, cell_st, nbr);
  gemm_qkv_mfma<<<dim3(384), dim3(256), 0, stream>>>(x, sidx, Bp, biasp, xqkv);
  fused_pt<<<dim3(N_PTS / 2), dim3(256), 0, stream>>>(
      sp4, sidx, rank, xqkv, nbr, pw1, pb1, pbng, pbnb, pbnm, pbnv, pw2, pb2,
      sc1, of1, l1wp, l1b, bn2g, bn2b, bn2m, bn2v, l2wp, l2b, out);
}